// Round 13
// baseline (5056.016 us; speedup 1.0000x reference)
//
#include <hip/hip_runtime.h>

#define NB 64
#define NT 1024
#define DIN 12
#define NH 256
#define NG 1024
#define NCLS 17
#define TCL 128
#define NCHUNK 8
#define XPS ((size_t)2 * NB * TCL * NG)   // floats per xp1 chunk buffer

typedef _Float16 f16;
typedef __attribute__((ext_vector_type(2))) _Float16 half2_t;
typedef __attribute__((ext_vector_type(8))) _Float16 f16x8;
typedef __attribute__((ext_vector_type(4))) float f32x4;
typedef unsigned int uint;
typedef unsigned short ushort;

__device__ __forceinline__ float sigm(float v) { return 1.0f / (1.0f + __expf(-v)); }
__device__ __forceinline__ float tanh_(float v) {
    v = fminf(fmaxf(v, -15.0f), 15.0f);
    float e = __expf(2.0f * v);
    return (e - 1.0f) / (e + 1.0f);
}
__device__ __forceinline__ float dot2(uint w, uint h, float c) {
    return __builtin_amdgcn_fdot2(__builtin_bit_cast(half2_t, w),
                                  __builtin_bit_cast(half2_t, h), c, false);
}
__device__ __forceinline__ uint pack16(float a, float b) {
    union { f16 h[2]; uint u; } cv; cv.h[0] = (f16)a; cv.h[1] = (f16)b; return cv.u;
}
__device__ __forceinline__ uint pkrtz(float a, float b) {
    return __builtin_bit_cast(uint, __builtin_amdgcn_cvt_pkrtz(a, b));
}
__device__ __forceinline__ ushort hbits(f16 v) {
    union { f16 h; ushort u; } cv; cv.h = v; return cv.u;
}
__device__ __forceinline__ uint rdlane(uint v, int l) {
    return (uint)__builtin_amdgcn_readlane((int)v, l);
}

// ---------------------------------------------------------------------------
// k_prep: layer-specific fp16 packing. kp = k/2 (0..127).
//  L0:  Wkv0 [dir][q][t][kp 0..35]    (VGPR, 144 uints/lane)
//       Wka0 [dir][q][t][kp 36..99]   (AGPR, 256 uints/lane)
//       Wkl0 [dir][q][g 0..6][t]u4    (LDS, kp=100+4g+j, 112 KB)
//       wih0p [dir][q][dp 0..5][t]    (input-proj pairs -> VGPR)
//  L1:  Wkv1 [dir][q][t][kp 0..47]    (VGPR, 192 uints/lane)
//       Wka1 [dir][q][t][kp 48..111]  (AGPR, 256 uints/lane)
//       Wkl1 [dir][q][g 0..3][t]u4    (LDS, kp=112+4g+j, 64 KB)
//  wih1h fp16 copy of w_ih1; bsum1 = b_ih1 + b_hh1
// ---------------------------------------------------------------------------
__global__ void k_prep(const float* __restrict__ w_hh0, const float* __restrict__ w_hh1,
                       const float* __restrict__ w_ih0, const float* __restrict__ w_ih1,
                       const float* __restrict__ b_ih1, const float* __restrict__ b_hh1,
                       uint* __restrict__ Wkv0, uint* __restrict__ Wka0,
                       uint* __restrict__ Wkl0, uint* __restrict__ wih0p,
                       uint* __restrict__ Wkv1, uint* __restrict__ Wka1,
                       uint* __restrict__ Wkl1,
                       f16* __restrict__ wih1h, float* __restrict__ bsum1) {
    int i = blockIdx.x * 256 + threadIdx.x;
    // ---- layer 0 ----
    if (i < 2 * 4 * 256 * 36) {            // Wkv0: 73728
        int kp = i % 36; int r = i / 36;
        int t = r & 255, q = (r >> 8) & 3, dir = r >> 10;
        const float* row = w_hh0 + (size_t)dir * NG * NH + (size_t)(q * 256 + t) * NH;
        Wkv0[i] = pack16(row[2 * kp], row[2 * kp + 1]);
    }
    if (i < 2 * 4 * 256 * 64) {            // Wka0: 131072
        int kp = 36 + (i % 64); int r = i / 64;
        int t = r & 255, q = (r >> 8) & 3, dir = r >> 10;
        const float* row = w_hh0 + (size_t)dir * NG * NH + (size_t)(q * 256 + t) * NH;
        Wka0[i] = pack16(row[2 * kp], row[2 * kp + 1]);
    }
    if (i < 2 * 4 * 7 * 256 * 4) {         // Wkl0: 57344
        int j = i & 3; int u = i >> 2;
        int t = u & 255; int v = u >> 8;
        int g = v % 7; int w2 = v / 7;
        int q = w2 & 3, dir = w2 >> 2;
        int kp = 100 + 4 * g + j;
        const float* row = w_hh0 + (size_t)dir * NG * NH + (size_t)(q * 256 + t) * NH;
        Wkl0[i] = pack16(row[2 * kp], row[2 * kp + 1]);
    }
    if (i < 2 * 4 * 6 * 256) {             // wih0p: 12288
        int t = i & 255; int r = i >> 8;
        int dp = r % 6, q = (r / 6) & 3, dd = r / 24;
        const float* row = w_ih0 + ((size_t)dd * NG + q * 256 + t) * DIN;
        wih0p[i] = pack16(row[2 * dp], row[2 * dp + 1]);
    }
    // ---- layer 1 ----
    if (i < 2 * 4 * 256 * 48) {            // Wkv1: 98304
        int kp = i % 48; int r = i / 48;
        int t = r & 255, q = (r >> 8) & 3, dir = r >> 10;
        const float* row = w_hh1 + (size_t)dir * NG * NH + (size_t)(q * 256 + t) * NH;
        Wkv1[i] = pack16(row[2 * kp], row[2 * kp + 1]);
    }
    if (i < 2 * 4 * 256 * 64) {            // Wka1: 131072 (kp 48..111)
        int kp = 48 + (i % 64); int r = i / 64;
        int t = r & 255, q = (r >> 8) & 3, dir = r >> 10;
        const float* row = w_hh1 + (size_t)dir * NG * NH + (size_t)(q * 256 + t) * NH;
        Wka1[i] = pack16(row[2 * kp], row[2 * kp + 1]);
    }
    if (i < 2 * 4 * 4 * 256 * 4) {         // Wkl1: 32768 (kp 112..127)
        int j = i & 3; int u = i >> 2;
        int t = u & 255; int v = u >> 8;
        int g = v & 3; int w2 = v >> 2;
        int q = w2 & 3, dir = w2 >> 2;
        int kp = 112 + 4 * g + j;
        const float* row = w_hh1 + (size_t)dir * NG * NH + (size_t)(q * 256 + t) * NH;
        Wkl1[i] = pack16(row[2 * kp], row[2 * kp + 1]);
    }
    if (i < 2 * NG * 2 * NH) wih1h[i] = (f16)w_ih1[i];
    if (i < 2 * NG) bsum1[i] = b_ih1[i] + b_hh1[i];
}

// ---- shared dot-group macros (readlane h-broadcast) ----------------------
#define VGRP(g8) { \
    uint s0 = rdlane(hvv.x, g8), s1 = rdlane(hvv.y, g8); \
    uint s2 = rdlane(hvv.z, g8), s3 = rdlane(hvv.w, g8); \
    _Pragma("unroll") for (int q = 0; q < 4; ++q) { \
        uint4 w = wrv[q][g8]; \
        ah[q] = dot2(w.x, s0, ah[q]); \
        ah[q] = dot2(w.y, s1, ah[q]); \
        ah[q] = dot2(w.z, s2, ah[q]); \
        ah[q] = dot2(w.w, s3, ah[q]); } }

#define AGRP(m, G8B) { \
    const int g8 = (G8B) + (m); \
    uint s0 = rdlane(hvv.x, g8), s1 = rdlane(hvv.y, g8); \
    uint s2 = rdlane(hvv.z, g8), s3 = rdlane(hvv.w, g8); \
    _Pragma("unroll") for (int q = 0; q < 4; ++q) { \
        uint w0, w1, w2, w3; \
        asm volatile("v_accvgpr_read_b32 %0, %1" : "=v"(w0) : "a"(aw[(q * 16 + (m)) * 4 + 0])); \
        asm volatile("v_accvgpr_read_b32 %0, %1" : "=v"(w1) : "a"(aw[(q * 16 + (m)) * 4 + 1])); \
        asm volatile("v_accvgpr_read_b32 %0, %1" : "=v"(w2) : "a"(aw[(q * 16 + (m)) * 4 + 2])); \
        asm volatile("v_accvgpr_read_b32 %0, %1" : "=v"(w3) : "a"(aw[(q * 16 + (m)) * 4 + 3])); \
        ah[q] = dot2(w0, s0, ah[q]); \
        ah[q] = dot2(w1, s1, ah[q]); \
        ah[q] = dot2(w2, s2, ah[q]); \
        ah[q] = dot2(w3, s3, ah[q]); } }

#define LISS(slot, g, NGRP) { \
    _Pragma("unroll") for (int q = 0; q < 4; ++q) \
        lw[slot][q] = wlds4[(q * (NGRP) + (g)) * 256 + tid]; }

#define LCON(slot, g, G8B) { \
    const int g8 = (G8B) + (g); \
    uint s0 = rdlane(hvv.x, g8), s1 = rdlane(hvv.y, g8); \
    uint s2 = rdlane(hvv.z, g8), s3 = rdlane(hvv.w, g8); \
    _Pragma("unroll") for (int q = 0; q < 4; ++q) { \
        uint4 w = lw[slot][q]; \
        ah[q] = dot2(w.x, s0, ah[q]); \
        ah[q] = dot2(w.y, s1, ah[q]); \
        ah[q] = dot2(w.z, s2, ah[q]); \
        ah[q] = dot2(w.w, s3, ah[q]); } }

// ---------------------------------------------------------------------------
// rec0_seq: layer-0. One block per (dir,batch), 256 thr. Lane t = unit t.
// Weights: 144 VGPR + 256 AGPR uints + 112 KB LDS, software-pipelined LDS
// reads (2-slot rolling buffer, issued >=3 dot-groups ahead; first 2 groups
// of each step issued before the previous barrier). One barrier/step.
// ---------------------------------------------------------------------------
__device__ void rec0_seq(char* smem, int rb,
                         const uint* __restrict__ Wkv0, const uint* __restrict__ Wka0,
                         const uint4* __restrict__ Wkl0, const uint* __restrict__ wih0p,
                         const float* __restrict__ b_ih0, const float* __restrict__ b_hh0,
                         const float* __restrict__ x, f16* __restrict__ out0h,
                         float* __restrict__ hst, float* __restrict__ cst) {
    uint4* wlds4 = (uint4*)smem;                         // [4][7][256] uint4 = 112 KB
    ushort* hs16 = (ushort*)(smem + 114688);             // [2 par][256] f16 = 1 KB

    const int tid = threadIdx.x;
    const int dir = rb >> 6;
    const int b = rb & 63;

    for (int n = tid; n < 7168; n += 256) wlds4[n] = Wkl0[dir * 7168 + n];

    uint4 wrv[4][9];
    #pragma unroll
    for (int q = 0; q < 4; ++q) {
        const uint* src = Wkv0 + (size_t)((dir * 4 + q) * 256 + tid) * 36;
        #pragma unroll
        for (int m = 0; m < 9; ++m) wrv[q][m] = *(const uint4*)(src + m * 4);
    }

    uint aw[256];
    #pragma unroll
    for (int q = 0; q < 4; ++q) {
        const uint* src = Wka0 + (size_t)((dir * 4 + q) * 256 + tid) * 64;
        #pragma unroll
        for (int m = 0; m < 16; ++m) {
            uint4 v = *(const uint4*)(src + m * 4);
            asm volatile("v_accvgpr_write_b32 %0, %1" : "=a"(aw[(q * 16 + m) * 4 + 0]) : "v"(v.x));
            asm volatile("v_accvgpr_write_b32 %0, %1" : "=a"(aw[(q * 16 + m) * 4 + 1]) : "v"(v.y));
            asm volatile("v_accvgpr_write_b32 %0, %1" : "=a"(aw[(q * 16 + m) * 4 + 2]) : "v"(v.z));
            asm volatile("v_accvgpr_write_b32 %0, %1" : "=a"(aw[(q * 16 + m) * 4 + 3]) : "v"(v.w));
        }
    }

    uint wihr[24];
    float bias[4];
    #pragma unroll
    for (int q = 0; q < 4; ++q) {
        #pragma unroll
        for (int dp = 0; dp < 6; ++dp)
            wihr[q * 6 + dp] = wih0p[((dir * 4 + q) * 6 + dp) * 256 + tid];
        bias[q] = b_ih0[dir * NG + q * 256 + tid] + b_hh0[dir * NG + q * 256 + tid];
    }

    const int sidx = (dir * NB + b) * NH + tid;
    float cv = 0.f, hv = 0.f;
    hs16[tid] = hbits((f16)0.f);
    __syncthreads();

    uint4 lw[2][4];
    LISS(0, 0, 7) LISS(1, 1, 7)

    #pragma unroll 1
    for (int it = 0; it < NT; ++it) {
        const int par = it & 1;
        uint4 hvv = ((const uint4*)(hs16 + par * 256))[tid & 31];

        float ah[4] = {0.f, 0.f, 0.f, 0.f};

        const int t = dir ? (NT - 1 - it) : it;
        const float4* xp = (const float4*)(x + ((size_t)b * NT + t) * DIN);
        float4 A = xp[0], B4 = xp[1], C4 = xp[2];
        float xv[12] = {A.x, A.y, A.z, A.w, B4.x, B4.y, B4.z, B4.w,
                        C4.x, C4.y, C4.z, C4.w};

        VGRP(0) VGRP(1) VGRP(2) VGRP(3) VGRP(4)
        VGRP(5) VGRP(6) VGRP(7) VGRP(8)
        LCON(0, 0, 25) LISS(0, 2, 7)
        AGRP(0, 9) AGRP(1, 9) AGRP(2, 9)
        LCON(1, 1, 25) LISS(1, 3, 7)
        AGRP(3, 9) AGRP(4, 9) AGRP(5, 9)
        LCON(0, 2, 25) LISS(0, 4, 7)
        AGRP(6, 9) AGRP(7, 9) AGRP(8, 9)
        LCON(1, 3, 25) LISS(1, 5, 7)
        AGRP(9, 9) AGRP(10, 9) AGRP(11, 9)
        LCON(0, 4, 25) LISS(0, 6, 7)
        AGRP(12, 9) AGRP(13, 9)
        LCON(1, 5, 25)
        AGRP(14, 9) AGRP(15, 9)
        LCON(0, 6, 25)
        LISS(0, 0, 7) LISS(1, 1, 7)      // prefetch next step (in flight across barrier)

        float z[4];
        uint xph[6];
        #pragma unroll
        for (int d = 0; d < 6; ++d) xph[d] = pkrtz(xv[2 * d], xv[2 * d + 1]);
        #pragma unroll
        for (int q = 0; q < 4; ++q) {
            float a = bias[q];
            #pragma unroll
            for (int d = 0; d < 6; ++d)
                a = dot2(wihr[q * 6 + d], xph[d], a);
            z[q] = ah[q] + a;
        }
        cv = sigm(z[1]) * cv + sigm(z[0]) * tanh_(z[2]);
        hv = sigm(z[3]) * tanh_(cv);

        f16 hi = (f16)hv;
        hs16[(par ^ 1) * 256 + tid] = hbits(hi);
        out0h[((size_t)b * NT + t) * 512 + dir * 256 + tid] = hi;
        __syncthreads();
    }

    cst[sidx] = cv; hst[sidx] = hv;
}

// ---------------------------------------------------------------------------
// rec1_seq: layer-1. Same structure: 192 VGPR + 256 AGPR uints + 64 KB LDS
// (16 b128/step), readlane h-broadcast, xq prefetched one step ahead.
// ---------------------------------------------------------------------------
__device__ void rec1_seq(char* smem, int rb, int chunk, int nsteps,
                         const uint* __restrict__ Wkv1, const uint* __restrict__ Wka1,
                         const uint4* __restrict__ Wkl1, const float* __restrict__ xp1,
                         float* __restrict__ hst, float* __restrict__ cst,
                         float* __restrict__ hsm) {
    uint4* wlds4 = (uint4*)smem;                         // [4][4][256] uint4 = 64 KB
    ushort* hs16 = (ushort*)(smem + 65536);              // [2 par][256] f16 = 1 KB

    const int tid = threadIdx.x;
    const int dir = rb >> 6;
    const int b = rb & 63;
    const int ld = 2 + dir;

    for (int n = tid; n < 4096; n += 256) wlds4[n] = Wkl1[dir * 4096 + n];

    uint4 wrv[4][12];
    #pragma unroll
    for (int q = 0; q < 4; ++q) {
        const uint* src = Wkv1 + (size_t)((dir * 4 + q) * 256 + tid) * 48;
        #pragma unroll
        for (int m = 0; m < 12; ++m) wrv[q][m] = *(const uint4*)(src + m * 4);
    }

    uint aw[256];
    #pragma unroll
    for (int q = 0; q < 4; ++q) {
        const uint* src = Wka1 + (size_t)((dir * 4 + q) * 256 + tid) * 64;
        #pragma unroll
        for (int m = 0; m < 16; ++m) {
            uint4 v = *(const uint4*)(src + m * 4);
            asm volatile("v_accvgpr_write_b32 %0, %1" : "=a"(aw[(q * 16 + m) * 4 + 0]) : "v"(v.x));
            asm volatile("v_accvgpr_write_b32 %0, %1" : "=a"(aw[(q * 16 + m) * 4 + 1]) : "v"(v.y));
            asm volatile("v_accvgpr_write_b32 %0, %1" : "=a"(aw[(q * 16 + m) * 4 + 2]) : "v"(v.z));
            asm volatile("v_accvgpr_write_b32 %0, %1" : "=a"(aw[(q * 16 + m) * 4 + 3]) : "v"(v.w));
        }
    }

    const int sidx = (ld * NB + b) * NH + tid;
    float cv, hv, hsv = 0.f;
    if (chunk == 0) { cv = 0.f; hv = 0.f; }
    else {
        cv = cst[sidx]; hv = hst[sidx];
        hsv = hsm[(dir * NB + b) * NH + tid];
    }
    hs16[tid] = hbits((f16)hv);

    const float* xbase = xp1 + ((size_t)dir * NB + b) * TCL * NG + tid * 4;
    float4 xq_cur = *(const float4*)xbase;
    __syncthreads();

    uint4 lw[2][4];
    LISS(0, 0, 4) LISS(1, 1, 4)

    #pragma unroll 1
    for (int it = 0; it < nsteps; ++it) {
        const int par = it & 1;
        uint4 hvv = ((const uint4*)(hs16 + par * 256))[tid & 31];

        const int itn = (it + 1 < nsteps) ? (it + 1) : it;
        float4 xq_nxt = *(const float4*)(xbase + (size_t)itn * NG);

        float ah[4] = {0.f, 0.f, 0.f, 0.f};

        VGRP(0) VGRP(1) VGRP(2) VGRP(3) VGRP(4) VGRP(5)
        VGRP(6) VGRP(7) VGRP(8) VGRP(9) VGRP(10) VGRP(11)
        LCON(0, 0, 28) LISS(0, 2, 4)
        AGRP(0, 12) AGRP(1, 12) AGRP(2, 12) AGRP(3, 12) AGRP(4, 12)
        LCON(1, 1, 28) LISS(1, 3, 4)
        AGRP(5, 12) AGRP(6, 12) AGRP(7, 12) AGRP(8, 12) AGRP(9, 12)
        LCON(0, 2, 28)
        AGRP(10, 12) AGRP(11, 12) AGRP(12, 12) AGRP(13, 12) AGRP(14, 12)
        LCON(1, 3, 28)
        AGRP(15, 12)
        LISS(0, 0, 4) LISS(1, 1, 4)      // prefetch next step

        float z0 = ah[0] + xq_cur.x;
        float z1 = ah[1] + xq_cur.y;
        float z2 = ah[2] + xq_cur.z;
        float z3 = ah[3] + xq_cur.w;
        cv = sigm(z1) * cv + sigm(z0) * tanh_(z2);
        hv = sigm(z3) * tanh_(cv);
        hsv += hv;

        hs16[(par ^ 1) * 256 + tid] = hbits((f16)hv);
        __syncthreads();
        xq_cur = xq_nxt;
    }

    cst[sidx] = cv; hst[sidx] = hv;
    hsm[(dir * NB + b) * NH + tid] = hsv;
}

// ---------------------------------------------------------------------------
// proj_role (chunk c): fp16 MFMA 16x16x32 direct-from-global (layout verified
// rounds 6-12). 128 role-blocks x 4 waves; wave handles 2 m-tiles. Stores xp1
// as [t][unit][gate] so rec1's per-step fetch is one coalesced float4.
// ---------------------------------------------------------------------------
__device__ void proj_role(int pb, int c,
                          const f16* __restrict__ out0h, const f16* __restrict__ wih1h,
                          const float* __restrict__ bsum1, float* __restrict__ xp1) {
    const int tid = threadIdx.x;
    const int w = tid >> 6, l = tid & 63;
    const int lane16 = l & 15, quad = l >> 4;

    #pragma unroll 1
    for (int mi = 0; mi < 2; ++mi) {
        const int mtg = pb * 8 + w * 2 + mi;       // 0..1023
        const int dirt = mtg >> 9;
        const int mtl = mtg & 511;

        const int ra = mtl * 16 + lane16;          // row over b(64) x tl(128)
        const int ab = ra >> 7, tla = ra & 127;
        const int ta = dirt ? (NT - 1 - c * TCL - tla) : (c * TCL + tla);
        const f16* Arow = out0h + ((size_t)ab * NT + ta) * 512 + quad * 8;

        uint4 afr[16];
        #pragma unroll
        for (int kt = 0; kt < 16; ++kt) afr[kt] = *(const uint4*)(Arow + kt * 32);

        int ob[4], otl[4];
        #pragma unroll
        for (int reg = 0; reg < 4; ++reg) {
            int rr = mtl * 16 + quad * 4 + reg;
            ob[reg] = rr >> 7; otl[reg] = rr & 127;
        }

        const f16* Bbase = wih1h + (size_t)dirt * NG * 512 + quad * 8;

        #pragma unroll 1
        for (int nt = 0; nt < 64; ++nt) {
            const int col = nt * 16 + lane16;
            const f16* Brow = Bbase + (size_t)col * 512;
            float bias = bsum1[dirt * NG + col];

            f32x4 acc = {0.f, 0.f, 0.f, 0.f};
            #pragma unroll
            for (int kt = 0; kt < 16; ++kt) {
                uint4 bv = *(const uint4*)(Brow + kt * 32);
                acc = __builtin_amdgcn_mfma_f32_16x16x32_f16(
                    __builtin_bit_cast(f16x8, afr[kt]),
                    __builtin_bit_cast(f16x8, bv), acc, 0, 0, 0);
            }
            const int ucol = col & 255, qcol = col >> 8;
            #pragma unroll
            for (int reg = 0; reg < 4; ++reg) {
                xp1[((size_t)(dirt * NB + ob[reg]) * TCL + otl[reg]) * NG
                    + ucol * 4 + qcol] = acc[reg] + bias;
            }
        }
    }
}

// ---------------------------------------------------------------------------
__global__ __launch_bounds__(256, 1) void k_rec0(
    const uint* __restrict__ Wkv0, const uint* __restrict__ Wka0,
    const uint4* __restrict__ Wkl0, const uint* __restrict__ wih0p,
    const float* __restrict__ b_ih0, const float* __restrict__ b_hh0,
    const float* __restrict__ x, f16* __restrict__ out0h,
    float* __restrict__ hst, float* __restrict__ cst) {
    extern __shared__ __align__(16) char smem[];
    rec0_seq(smem, blockIdx.x, Wkv0, Wka0, Wkl0, wih0p, b_ih0, b_hh0,
             x, out0h, hst, cst);
}

// ---------------------------------------------------------------------------
__global__ __launch_bounds__(256, 1) void k_pipe(
    int j,
    const uint* __restrict__ Wkv1, const uint* __restrict__ Wka1,
    const uint4* __restrict__ Wkl1,
    const f16* __restrict__ out0h, const f16* __restrict__ wih1h,
    const float* __restrict__ bsum1, float* __restrict__ xp1,
    float* __restrict__ hst, float* __restrict__ cst, float* __restrict__ hsm) {
    extern __shared__ __align__(16) char smem[];
    const int bid = blockIdx.x;
    if (bid < 128) {
        const int cc = j - 1;
        if (cc >= 0 && cc < NCHUNK)
            rec1_seq(smem, bid, cc, TCL, Wkv1, Wka1, Wkl1,
                     xp1 + (size_t)(cc & 1) * XPS, hst, cst, hsm);
    } else {
        const int cp = j;
        if (cp < NCHUNK)
            proj_role(bid - 128, cp, out0h, wih1h, bsum1,
                      xp1 + (size_t)(cp & 1) * XPS);
    }
}

// ---------------------------------------------------------------------------
__global__ void k_fc(const float* __restrict__ hsm, const float* __restrict__ fc_w,
                     const float* __restrict__ fc_b, float* __restrict__ out) {
    const int b = blockIdx.x;
    const int n = threadIdx.x;
    if (n >= NCLS) return;
    float acc = fc_b[n];
    const float inv = 1.0f / (float)NT;
    for (int k = 0; k < 2 * NH; ++k) {
        float pv = hsm[((k >> 8) * NB + b) * NH + (k & 255)];
        acc += (pv * inv) * fc_w[n * 2 * NH + k];
    }
    out[b * NCLS + n] = acc;
}

// ---------------------------------------------------------------------------
extern "C" void kernel_launch(void* const* d_in, const int* in_sizes, int n_in,
                              void* d_out, int out_size, void* d_ws, size_t ws_size,
                              hipStream_t stream) {
    const float* x     = (const float*)d_in[0];
    const float* w_ih0 = (const float*)d_in[1];
    const float* w_hh0 = (const float*)d_in[2];
    const float* b_ih0 = (const float*)d_in[3];
    const float* b_hh0 = (const float*)d_in[4];
    const float* w_ih1 = (const float*)d_in[5];
    const float* w_hh1 = (const float*)d_in[6];
    const float* b_ih1 = (const float*)d_in[7];
    const float* b_hh1 = (const float*)d_in[8];
    const float* fc_w  = (const float*)d_in[9];
    const float* fc_b  = (const float*)d_in[10];
    float* out = (float*)d_out;

    char* ws = (char*)d_ws;
    uint* Wkv0  = (uint*)ws;                      // 73728 u
    uint* Wka0  = Wkv0 + 73728;                   // 131072 u
    uint* Wkl0  = Wka0 + 131072;                  // 57344 u
    uint* wih0p = Wkl0 + 57344;                   // 12288 u
    uint* Wkv1  = wih0p + 12288;                  // 98304 u
    uint* Wka1  = Wkv1 + 98304;                   // 131072 u
    uint* Wkl1  = Wka1 + 131072;                  // 32768 u
    f16* wih1h  = (f16*)(Wkl1 + 32768);           // 1048576 h = 2 MB
    float* bsum1 = (float*)(wih1h + 1048576);     // 2048 f
    float* hst  = bsum1 + 2048;                   // 65536 f
    float* cst  = hst + 65536;                    // 65536 f
    float* hsm  = cst + 65536;                    // 32768 f
    float* xp1  = hsm + 32768;                    // 2 x 16777216 f = 128 MB
    f16* out0h  = (f16*)(xp1 + 2 * XPS);          // 33554432 h = 64 MB

    k_prep<<<dim3(4096), dim3(256), 0, stream>>>(
        w_hh0, w_hh1, w_ih0, w_ih1, b_ih1, b_hh1,
        Wkv0, Wka0, Wkl0, wih0p, Wkv1, Wka1, Wkl1, wih1h, bsum1);

    k_rec0<<<dim3(128), dim3(256), 115712, stream>>>(
        Wkv0, Wka0, (const uint4*)Wkl0, wih0p, b_ih0, b_hh0, x, out0h, hst, cst);

    for (int j = 0; j <= NCHUNK; ++j) {
        k_pipe<<<dim3(256), dim3(256), 66560, stream>>>(
            j, Wkv1, Wka1, (const uint4*)Wkl1, out0h, wih1h, bsum1,
            xp1, hst, cst, hsm);
    }

    k_fc<<<dim3(64), dim3(32), 0, stream>>>(hsm, fc_w, fc_b, out);
}

// Round 14
// 4853.001 us; speedup vs baseline: 1.0418x; 1.0418x over previous
//
#include <hip/hip_runtime.h>

#define NB 64
#define NT 1024
#define DIN 12
#define NH 256
#define NG 1024
#define NCLS 17
#define TCL 128
#define NCHUNK 8
#define XPS ((size_t)2 * NB * TCL * NG)   // floats per xp1 chunk buffer

typedef _Float16 f16;
typedef __attribute__((ext_vector_type(2))) _Float16 half2_t;
typedef __attribute__((ext_vector_type(8))) _Float16 f16x8;
typedef __attribute__((ext_vector_type(4))) float f32x4;
typedef unsigned int uint;
typedef unsigned short ushort;

__device__ __forceinline__ float sigm(float v) { return 1.0f / (1.0f + __expf(-v)); }
__device__ __forceinline__ float tanh_(float v) {
    v = fminf(fmaxf(v, -15.0f), 15.0f);
    float e = __expf(2.0f * v);
    return (e - 1.0f) / (e + 1.0f);
}
__device__ __forceinline__ float dot2(uint w, uint h, float c) {
    return __builtin_amdgcn_fdot2(__builtin_bit_cast(half2_t, w),
                                  __builtin_bit_cast(half2_t, h), c, false);
}
__device__ __forceinline__ uint pack16(float a, float b) {
    union { f16 h[2]; uint u; } cv; cv.h[0] = (f16)a; cv.h[1] = (f16)b; return cv.u;
}
__device__ __forceinline__ uint pkrtz(float a, float b) {
    return __builtin_bit_cast(uint, __builtin_amdgcn_cvt_pkrtz(a, b));
}
__device__ __forceinline__ ushort hbits(f16 v) {
    union { f16 h; ushort u; } cv; cv.h = v; return cv.u;
}
__device__ __forceinline__ uint rdlane(uint v, int l) {
    return (uint)__builtin_amdgcn_readlane((int)v, l);
}

// ---------------------------------------------------------------------------
// k_prep: layer-specific fp16 packing (round-12 layouts). kp = k/2 (0..127).
//  L0:  Wkv0 [dir][q][t][kp 0..39]    (VGPR, 160 uints/lane)
//       Wka0 [dir][q][t][kp 40..99]   (AGPR, 240 uints/lane)
//       Wkl0 [dir][q][g 0..6][t]u4    (LDS, kp=100+4g+j, 112 KB)
//       wih0p [dir][q][dp 0..5][t]    (input-proj pairs -> VGPR)
//  L1:  Wkv1 [dir][q][t][kp 0..47]    (VGPR, 192 uints/lane)
//       Wka1 [dir][q][t][kp 48..107]  (AGPR, 240 uints/lane)
//       Wkl1 [dir][q][g 0..4][t]u4    (LDS, kp=108+4g+j, 80 KB)
//  wih1h fp16 copy of w_ih1; bsum1 = b_ih1 + b_hh1
// ---------------------------------------------------------------------------
__global__ void k_prep(const float* __restrict__ w_hh0, const float* __restrict__ w_hh1,
                       const float* __restrict__ w_ih0, const float* __restrict__ w_ih1,
                       const float* __restrict__ b_ih1, const float* __restrict__ b_hh1,
                       uint* __restrict__ Wkv0, uint* __restrict__ Wka0,
                       uint* __restrict__ Wkl0, uint* __restrict__ wih0p,
                       uint* __restrict__ Wkv1, uint* __restrict__ Wka1,
                       uint* __restrict__ Wkl1,
                       f16* __restrict__ wih1h, float* __restrict__ bsum1) {
    int i = blockIdx.x * 256 + threadIdx.x;
    // ---- layer 0 ----
    if (i < 2 * 4 * 256 * 40) {            // Wkv0
        int kp = i % 40; int r = i / 40;
        int t = r & 255, q = (r >> 8) & 3, dir = r >> 10;
        const float* row = w_hh0 + (size_t)dir * NG * NH + (size_t)(q * 256 + t) * NH;
        Wkv0[i] = pack16(row[2 * kp], row[2 * kp + 1]);
    }
    if (i < 2 * 4 * 256 * 60) {            // Wka0
        int kp = 40 + (i % 60); int r = i / 60;
        int t = r & 255, q = (r >> 8) & 3, dir = r >> 10;
        const float* row = w_hh0 + (size_t)dir * NG * NH + (size_t)(q * 256 + t) * NH;
        Wka0[i] = pack16(row[2 * kp], row[2 * kp + 1]);
    }
    if (i < 2 * 4 * 7 * 256 * 4) {         // Wkl0
        int j = i & 3; int u = i >> 2;
        int t = u & 255; int v = u >> 8;
        int g = v % 7; int w2 = v / 7;
        int q = w2 & 3, dir = w2 >> 2;
        int kp = 100 + 4 * g + j;
        const float* row = w_hh0 + (size_t)dir * NG * NH + (size_t)(q * 256 + t) * NH;
        Wkl0[i] = pack16(row[2 * kp], row[2 * kp + 1]);
    }
    if (i < 2 * 4 * 6 * 256) {             // wih0p
        int t = i & 255; int r = i >> 8;
        int dp = r % 6, q = (r / 6) & 3, dd = r / 24;
        const float* row = w_ih0 + ((size_t)dd * NG + q * 256 + t) * DIN;
        wih0p[i] = pack16(row[2 * dp], row[2 * dp + 1]);
    }
    // ---- layer 1 ----
    if (i < 2 * 4 * 256 * 48) {            // Wkv1
        int kp = i % 48; int r = i / 48;
        int t = r & 255, q = (r >> 8) & 3, dir = r >> 10;
        const float* row = w_hh1 + (size_t)dir * NG * NH + (size_t)(q * 256 + t) * NH;
        Wkv1[i] = pack16(row[2 * kp], row[2 * kp + 1]);
    }
    if (i < 2 * 4 * 256 * 60) {            // Wka1 (kp 48..107)
        int kp = 48 + (i % 60); int r = i / 60;
        int t = r & 255, q = (r >> 8) & 3, dir = r >> 10;
        const float* row = w_hh1 + (size_t)dir * NG * NH + (size_t)(q * 256 + t) * NH;
        Wka1[i] = pack16(row[2 * kp], row[2 * kp + 1]);
    }
    if (i < 2 * 4 * 5 * 256 * 4) {         // Wkl1 (kp 108..127)
        int j = i & 3; int u = i >> 2;
        int t = u & 255; int v = u >> 8;
        int g = v % 5; int w2 = v / 5;
        int q = w2 & 3, dir = w2 >> 2;
        int kp = 108 + 4 * g + j;
        const float* row = w_hh1 + (size_t)dir * NG * NH + (size_t)(q * 256 + t) * NH;
        Wkl1[i] = pack16(row[2 * kp], row[2 * kp + 1]);
    }
    if (i < 2 * NG * 2 * NH) wih1h[i] = (f16)w_ih1[i];
    if (i < 2 * NG) bsum1[i] = b_ih1[i] + b_hh1[i];
}

// ---------------------------------------------------------------------------
// rec0_seq: layer-0 (round-12/10 variant, measured 2.24 us/step) + delayed
// out0h store: h(t) is stored at the TOP of step t+1 so the global store has
// a full step to drain before the barrier's vmcnt(0) can wait on it.
// One block per (dir,batch), 256 threads. Lane t owns unit t (4 gate rows).
// Weights: 160 VGPR + 240 AGPR uints + 112 KB LDS. h broadcast: one b128
// LDS read/lane + readlane -> SGPR operand of v_dot2. One barrier/step.
// ---------------------------------------------------------------------------
__device__ void rec0_seq(char* smem, int rb,
                         const uint* __restrict__ Wkv0, const uint* __restrict__ Wka0,
                         const uint4* __restrict__ Wkl0, const uint* __restrict__ wih0p,
                         const float* __restrict__ b_ih0, const float* __restrict__ b_hh0,
                         const float* __restrict__ x, f16* __restrict__ out0h,
                         float* __restrict__ hst, float* __restrict__ cst) {
    uint4* wlds4 = (uint4*)smem;                         // [4][7][256] uint4 = 112 KB
    ushort* hs16 = (ushort*)(smem + 114688);             // [2 par][256] f16 = 1 KB

    const int tid = threadIdx.x;
    const int dir = rb >> 6;
    const int b = rb & 63;

    for (int n = tid; n < 7168; n += 256) wlds4[n] = Wkl0[dir * 7168 + n];

    uint4 wrv[4][10];
    #pragma unroll
    for (int q = 0; q < 4; ++q) {
        const uint* src = Wkv0 + (size_t)((dir * 4 + q) * 256 + tid) * 40;
        #pragma unroll
        for (int m = 0; m < 10; ++m) wrv[q][m] = *(const uint4*)(src + m * 4);
    }

    uint aw[240];
    #pragma unroll
    for (int q = 0; q < 4; ++q) {
        const uint* src = Wka0 + (size_t)((dir * 4 + q) * 256 + tid) * 60;
        #pragma unroll
        for (int m = 0; m < 15; ++m) {
            uint4 v = *(const uint4*)(src + m * 4);
            asm volatile("v_accvgpr_write_b32 %0, %1" : "=a"(aw[(q * 15 + m) * 4 + 0]) : "v"(v.x));
            asm volatile("v_accvgpr_write_b32 %0, %1" : "=a"(aw[(q * 15 + m) * 4 + 1]) : "v"(v.y));
            asm volatile("v_accvgpr_write_b32 %0, %1" : "=a"(aw[(q * 15 + m) * 4 + 2]) : "v"(v.z));
            asm volatile("v_accvgpr_write_b32 %0, %1" : "=a"(aw[(q * 15 + m) * 4 + 3]) : "v"(v.w));
        }
    }

    uint wihr[24];
    float bias[4];
    #pragma unroll
    for (int q = 0; q < 4; ++q) {
        #pragma unroll
        for (int dp = 0; dp < 6; ++dp)
            wihr[q * 6 + dp] = wih0p[((dir * 4 + q) * 6 + dp) * 256 + tid];
        bias[q] = b_ih0[dir * NG + q * 256 + tid] + b_hh0[dir * NG + q * 256 + tid];
    }

    const int sidx = (dir * NB + b) * NH + tid;
    float cv = 0.f, hv = 0.f;
    hs16[tid] = hbits((f16)0.f);
    __syncthreads();

    f16 hi_prev = (f16)0.f;
    int t_prev = 0;

    #pragma unroll 1
    for (int it = 0; it < NT; ++it) {
        const int par = it & 1;
        uint4 hvv = ((const uint4*)(hs16 + par * 256))[tid & 31];

        const int t = dir ? (NT - 1 - it) : it;

        // delayed store of previous step's h — drains during this whole step
        if (it > 0)
            out0h[((size_t)b * NT + t_prev) * 512 + dir * 256 + tid] = hi_prev;

        float ah[4] = {0.f, 0.f, 0.f, 0.f};

        const float4* xp = (const float4*)(x + ((size_t)b * NT + t) * DIN);
        float4 A = xp[0], B4 = xp[1], C4 = xp[2];
        float xv[12] = {A.x, A.y, A.z, A.w, B4.x, B4.y, B4.z, B4.w,
                        C4.x, C4.y, C4.z, C4.w};

        #pragma unroll
        for (int g8 = 0; g8 < 10; ++g8) {
            uint s0 = rdlane(hvv.x, g8), s1 = rdlane(hvv.y, g8);
            uint s2 = rdlane(hvv.z, g8), s3 = rdlane(hvv.w, g8);
            #pragma unroll
            for (int q = 0; q < 4; ++q) {
                uint4 w = wrv[q][g8];
                ah[q] = dot2(w.x, s0, ah[q]);
                ah[q] = dot2(w.y, s1, ah[q]);
                ah[q] = dot2(w.z, s2, ah[q]);
                ah[q] = dot2(w.w, s3, ah[q]);
            }
        }
        #pragma unroll
        for (int m = 0; m < 15; ++m) {
            const int g8 = 10 + m;
            uint s0 = rdlane(hvv.x, g8), s1 = rdlane(hvv.y, g8);
            uint s2 = rdlane(hvv.z, g8), s3 = rdlane(hvv.w, g8);
            #pragma unroll
            for (int q = 0; q < 4; ++q) {
                uint w0, w1, w2, w3;
                asm volatile("v_accvgpr_read_b32 %0, %1" : "=v"(w0) : "a"(aw[(q * 15 + m) * 4 + 0]));
                asm volatile("v_accvgpr_read_b32 %0, %1" : "=v"(w1) : "a"(aw[(q * 15 + m) * 4 + 1]));
                asm volatile("v_accvgpr_read_b32 %0, %1" : "=v"(w2) : "a"(aw[(q * 15 + m) * 4 + 2]));
                asm volatile("v_accvgpr_read_b32 %0, %1" : "=v"(w3) : "a"(aw[(q * 15 + m) * 4 + 3]));
                ah[q] = dot2(w0, s0, ah[q]);
                ah[q] = dot2(w1, s1, ah[q]);
                ah[q] = dot2(w2, s2, ah[q]);
                ah[q] = dot2(w3, s3, ah[q]);
            }
        }
        #pragma unroll
        for (int g = 0; g < 7; ++g) {
            const int g8 = 25 + g;
            uint s0 = rdlane(hvv.x, g8), s1 = rdlane(hvv.y, g8);
            uint s2 = rdlane(hvv.z, g8), s3 = rdlane(hvv.w, g8);
            #pragma unroll
            for (int q = 0; q < 4; ++q) {
                uint4 w = wlds4[(q * 7 + g) * 256 + tid];
                ah[q] = dot2(w.x, s0, ah[q]);
                ah[q] = dot2(w.y, s1, ah[q]);
                ah[q] = dot2(w.z, s2, ah[q]);
                ah[q] = dot2(w.w, s3, ah[q]);
            }
        }

        float z[4];
        uint xph[6];
        #pragma unroll
        for (int d = 0; d < 6; ++d) xph[d] = pkrtz(xv[2 * d], xv[2 * d + 1]);
        #pragma unroll
        for (int q = 0; q < 4; ++q) {
            float a = bias[q];
            #pragma unroll
            for (int d = 0; d < 6; ++d)
                a = dot2(wihr[q * 6 + d], xph[d], a);
            z[q] = ah[q] + a;
        }
        cv = sigm(z[1]) * cv + sigm(z[0]) * tanh_(z[2]);
        hv = sigm(z[3]) * tanh_(cv);

        f16 hi = (f16)hv;
        hs16[(par ^ 1) * 256 + tid] = hbits(hi);
        hi_prev = hi;
        t_prev = t;
        __syncthreads();
    }

    out0h[((size_t)b * NT + t_prev) * 512 + dir * 256 + tid] = hi_prev;
    cst[sidx] = cv; hst[sidx] = hv;
}

// ---------------------------------------------------------------------------
// rec1_seq: layer-1 recurrence (round-12 exact — measured ~255 us/launch).
// One block per (dir,batch), 256 threads. Weights: 192 VGPR + 240 AGPR uints
// + 80 KB LDS. h via LDS broadcast reads; xq prefetched one full step ahead
// (drained by barrier time). One barrier per step.
// ---------------------------------------------------------------------------
__device__ void rec1_seq(char* smem, int rb, int chunk, int nsteps,
                         const uint* __restrict__ Wkv1, const uint* __restrict__ Wka1,
                         const uint4* __restrict__ Wkl1, const float* __restrict__ xp1,
                         float* __restrict__ hst, float* __restrict__ cst,
                         float* __restrict__ hsm) {
    uint4* wlds4 = (uint4*)smem;                         // [4][5][256] uint4 = 80 KB
    ushort* hs16 = (ushort*)(smem + 81920);              // [2 par][256] f16 = 1 KB

    const int tid = threadIdx.x;
    const int dir = rb >> 6;
    const int b = rb & 63;
    const int ld = 2 + dir;

    for (int n = tid; n < 5120; n += 256) wlds4[n] = Wkl1[dir * 5120 + n];

    uint4 wrv[4][12];
    #pragma unroll
    for (int q = 0; q < 4; ++q) {
        const uint* src = Wkv1 + (size_t)((dir * 4 + q) * 256 + tid) * 48;
        #pragma unroll
        for (int m = 0; m < 12; ++m) wrv[q][m] = *(const uint4*)(src + m * 4);
    }

    uint aw[240];
    #pragma unroll
    for (int q = 0; q < 4; ++q) {
        const uint* src = Wka1 + (size_t)((dir * 4 + q) * 256 + tid) * 60;
        #pragma unroll
        for (int m = 0; m < 15; ++m) {
            uint4 v = *(const uint4*)(src + m * 4);
            asm volatile("v_accvgpr_write_b32 %0, %1" : "=a"(aw[(q * 15 + m) * 4 + 0]) : "v"(v.x));
            asm volatile("v_accvgpr_write_b32 %0, %1" : "=a"(aw[(q * 15 + m) * 4 + 1]) : "v"(v.y));
            asm volatile("v_accvgpr_write_b32 %0, %1" : "=a"(aw[(q * 15 + m) * 4 + 2]) : "v"(v.z));
            asm volatile("v_accvgpr_write_b32 %0, %1" : "=a"(aw[(q * 15 + m) * 4 + 3]) : "v"(v.w));
        }
    }

    const int sidx = (ld * NB + b) * NH + tid;
    float cv, hv, hsv = 0.f;
    if (chunk == 0) { cv = 0.f; hv = 0.f; }
    else {
        cv = cst[sidx]; hv = hst[sidx];
        hsv = hsm[(dir * NB + b) * NH + tid];
    }
    hs16[tid] = hbits((f16)hv);

    const float* xbase = xp1 + ((size_t)dir * NB + b) * TCL * NG + tid * 4;
    float4 xq_cur = *(const float4*)xbase;
    __syncthreads();

    #pragma unroll 1
    for (int it = 0; it < nsteps; ++it) {
        const int par = it & 1;
        const uint4* Hh = (const uint4*)(hs16 + par * 256);

        const int itn = (it + 1 < nsteps) ? (it + 1) : it;
        float4 xq_nxt = *(const float4*)(xbase + (size_t)itn * NG);

        float ah[4] = {0.f, 0.f, 0.f, 0.f};

        // ---- VGPR region: g8 0..11 (kp 0..47) ----
        #pragma unroll
        for (int g8 = 0; g8 < 12; ++g8) {
            uint4 H = Hh[g8];
            #pragma unroll
            for (int q = 0; q < 4; ++q) {
                uint4 w = wrv[q][g8];
                ah[q] = dot2(w.x, H.x, ah[q]);
                ah[q] = dot2(w.y, H.y, ah[q]);
                ah[q] = dot2(w.z, H.z, ah[q]);
                ah[q] = dot2(w.w, H.w, ah[q]);
            }
        }
        // ---- AGPR region: g8 12..26 (kp 48..107) ----
        #pragma unroll
        for (int m = 0; m < 15; ++m) {
            const int g8 = 12 + m;
            uint4 H = Hh[g8];
            #pragma unroll
            for (int q = 0; q < 4; ++q) {
                uint w0, w1, w2, w3;
                asm volatile("v_accvgpr_read_b32 %0, %1" : "=v"(w0) : "a"(aw[(q * 15 + m) * 4 + 0]));
                asm volatile("v_accvgpr_read_b32 %0, %1" : "=v"(w1) : "a"(aw[(q * 15 + m) * 4 + 1]));
                asm volatile("v_accvgpr_read_b32 %0, %1" : "=v"(w2) : "a"(aw[(q * 15 + m) * 4 + 2]));
                asm volatile("v_accvgpr_read_b32 %0, %1" : "=v"(w3) : "a"(aw[(q * 15 + m) * 4 + 3]));
                ah[q] = dot2(w0, H.x, ah[q]);
                ah[q] = dot2(w1, H.y, ah[q]);
                ah[q] = dot2(w2, H.z, ah[q]);
                ah[q] = dot2(w3, H.w, ah[q]);
            }
        }
        // ---- LDS region: g8 27..31 (kp 108..127) ----
        #pragma unroll
        for (int g = 0; g < 5; ++g) {
            const int g8 = 27 + g;
            uint4 H = Hh[g8];
            #pragma unroll
            for (int q = 0; q < 4; ++q) {
                uint4 w = wlds4[(q * 5 + g) * 256 + tid];
                ah[q] = dot2(w.x, H.x, ah[q]);
                ah[q] = dot2(w.y, H.y, ah[q]);
                ah[q] = dot2(w.z, H.z, ah[q]);
                ah[q] = dot2(w.w, H.w, ah[q]);
            }
        }

        float z0 = ah[0] + xq_cur.x;
        float z1 = ah[1] + xq_cur.y;
        float z2 = ah[2] + xq_cur.z;
        float z3 = ah[3] + xq_cur.w;
        cv = sigm(z1) * cv + sigm(z0) * tanh_(z2);
        hv = sigm(z3) * tanh_(cv);
        hsv += hv;

        hs16[(par ^ 1) * 256 + tid] = hbits((f16)hv);
        __syncthreads();
        xq_cur = xq_nxt;
    }

    cst[sidx] = cv; hst[sidx] = hv;
    hsm[(dir * NB + b) * NH + tid] = hsv;
}

// ---------------------------------------------------------------------------
// proj_role (chunk c): fp16 MFMA 16x16x32 direct-from-global (layout verified
// rounds 6-13). 128 role-blocks x 4 waves; wave handles 2 m-tiles. Stores xp1
// as [t][unit][gate] so rec1's per-step fetch is one coalesced float4.
// ---------------------------------------------------------------------------
__device__ void proj_role(int pb, int c,
                          const f16* __restrict__ out0h, const f16* __restrict__ wih1h,
                          const float* __restrict__ bsum1, float* __restrict__ xp1) {
    const int tid = threadIdx.x;
    const int w = tid >> 6, l = tid & 63;
    const int lane16 = l & 15, quad = l >> 4;

    #pragma unroll 1
    for (int mi = 0; mi < 2; ++mi) {
        const int mtg = pb * 8 + w * 2 + mi;       // 0..1023
        const int dirt = mtg >> 9;
        const int mtl = mtg & 511;

        const int ra = mtl * 16 + lane16;          // row over b(64) x tl(128)
        const int ab = ra >> 7, tla = ra & 127;
        const int ta = dirt ? (NT - 1 - c * TCL - tla) : (c * TCL + tla);
        const f16* Arow = out0h + ((size_t)ab * NT + ta) * 512 + quad * 8;

        uint4 afr[16];
        #pragma unroll
        for (int kt = 0; kt < 16; ++kt) afr[kt] = *(const uint4*)(Arow + kt * 32);

        int ob[4], otl[4];
        #pragma unroll
        for (int reg = 0; reg < 4; ++reg) {
            int rr = mtl * 16 + quad * 4 + reg;
            ob[reg] = rr >> 7; otl[reg] = rr & 127;
        }

        const f16* Bbase = wih1h + (size_t)dirt * NG * 512 + quad * 8;

        #pragma unroll 1
        for (int nt = 0; nt < 64; ++nt) {
            const int col = nt * 16 + lane16;
            const f16* Brow = Bbase + (size_t)col * 512;
            float bias = bsum1[dirt * NG + col];

            f32x4 acc = {0.f, 0.f, 0.f, 0.f};
            #pragma unroll
            for (int kt = 0; kt < 16; ++kt) {
                uint4 bv = *(const uint4*)(Brow + kt * 32);
                acc = __builtin_amdgcn_mfma_f32_16x16x32_f16(
                    __builtin_bit_cast(f16x8, afr[kt]),
                    __builtin_bit_cast(f16x8, bv), acc, 0, 0, 0);
            }
            const int ucol = col & 255, qcol = col >> 8;
            #pragma unroll
            for (int reg = 0; reg < 4; ++reg) {
                xp1[((size_t)(dirt * NB + ob[reg]) * TCL + otl[reg]) * NG
                    + ucol * 4 + qcol] = acc[reg] + bias;
            }
        }
    }
}

// ---------------------------------------------------------------------------
__global__ __launch_bounds__(256, 1) void k_rec0(
    const uint* __restrict__ Wkv0, const uint* __restrict__ Wka0,
    const uint4* __restrict__ Wkl0, const uint* __restrict__ wih0p,
    const float* __restrict__ b_ih0, const float* __restrict__ b_hh0,
    const float* __restrict__ x, f16* __restrict__ out0h,
    float* __restrict__ hst, float* __restrict__ cst) {
    extern __shared__ __align__(16) char smem[];
    rec0_seq(smem, blockIdx.x, Wkv0, Wka0, Wkl0, wih0p, b_ih0, b_hh0,
             x, out0h, hst, cst);
}

// ---------------------------------------------------------------------------
__global__ __launch_bounds__(256, 1) void k_pipe(
    int j,
    const uint* __restrict__ Wkv1, const uint* __restrict__ Wka1,
    const uint4* __restrict__ Wkl1,
    const f16* __restrict__ out0h, const f16* __restrict__ wih1h,
    const float* __restrict__ bsum1, float* __restrict__ xp1,
    float* __restrict__ hst, float* __restrict__ cst, float* __restrict__ hsm) {
    extern __shared__ __align__(16) char smem[];
    const int bid = blockIdx.x;
    if (bid < 128) {
        const int cc = j - 1;
        if (cc >= 0 && cc < NCHUNK)
            rec1_seq(smem, bid, cc, TCL, Wkv1, Wka1, Wkl1,
                     xp1 + (size_t)(cc & 1) * XPS, hst, cst, hsm);
    } else {
        const int cp = j;
        if (cp < NCHUNK)
            proj_role(bid - 128, cp, out0h, wih1h, bsum1,
                      xp1 + (size_t)(cp & 1) * XPS);
    }
}

// ---------------------------------------------------------------------------
__global__ void k_fc(const float* __restrict__ hsm, const float* __restrict__ fc_w,
                     const float* __restrict__ fc_b, float* __restrict__ out) {
    const int b = blockIdx.x;
    const int n = threadIdx.x;
    if (n >= NCLS) return;
    float acc = fc_b[n];
    const float inv = 1.0f / (float)NT;
    for (int k = 0; k < 2 * NH; ++k) {
        float pv = hsm[((k >> 8) * NB + b) * NH + (k & 255)];
        acc += (pv * inv) * fc_w[n * 2 * NH + k];
    }
    out[b * NCLS + n] = acc;
}

// ---------------------------------------------------------------------------
extern "C" void kernel_launch(void* const* d_in, const int* in_sizes, int n_in,
                              void* d_out, int out_size, void* d_ws, size_t ws_size,
                              hipStream_t stream) {
    const float* x     = (const float*)d_in[0];
    const float* w_ih0 = (const float*)d_in[1];
    const float* w_hh0 = (const float*)d_in[2];
    const float* b_ih0 = (const float*)d_in[3];
    const float* b_hh0 = (const float*)d_in[4];
    const float* w_ih1 = (const float*)d_in[5];
    const float* w_hh1 = (const float*)d_in[6];
    const float* b_ih1 = (const float*)d_in[7];
    const float* b_hh1 = (const float*)d_in[8];
    const float* fc_w  = (const float*)d_in[9];
    const float* fc_b  = (const float*)d_in[10];
    float* out = (float*)d_out;

    char* ws = (char*)d_ws;
    uint* Wkv0  = (uint*)ws;                      // 81920 u
    uint* Wka0  = Wkv0 + 81920;                   // 122880 u
    uint* Wkl0  = Wka0 + 122880;                  // 57344 u
    uint* wih0p = Wkl0 + 57344;                   // 12288 u
    uint* Wkv1  = wih0p + 12288;                  // 98304 u
    uint* Wka1  = Wkv1 + 98304;                   // 122880 u
    uint* Wkl1  = Wka1 + 122880;                  // 40960 u
    f16* wih1h  = (f16*)(Wkl1 + 40960);           // 1048576 h = 2 MB
    float* bsum1 = (float*)(wih1h + 1048576);     // 2048 f
    float* hst  = bsum1 + 2048;                   // 65536 f
    float* cst  = hst + 65536;                    // 65536 f
    float* hsm  = cst + 65536;                    // 32768 f
    float* xp1  = hsm + 32768;                    // 2 x 16777216 f = 128 MB
    f16* out0h  = (f16*)(xp1 + 2 * XPS);          // 33554432 h = 64 MB

    k_prep<<<dim3(4096), dim3(256), 0, stream>>>(
        w_hh0, w_hh1, w_ih0, w_ih1, b_ih1, b_hh1,
        Wkv0, Wka0, Wkl0, wih0p, Wkv1, Wka1, Wkl1, wih1h, bsum1);

    k_rec0<<<dim3(128), dim3(256), 115712, stream>>>(
        Wkv0, Wka0, (const uint4*)Wkl0, wih0p, b_ih0, b_hh0, x, out0h, hst, cst);

    for (int j = 0; j <= NCHUNK; ++j) {
        k_pipe<<<dim3(256), dim3(256), 82944, stream>>>(
            j, Wkv1, Wka1, (const uint4*)Wkl1, out0h, wih1h, bsum1,
            xp1, hst, cst, hsm);
    }

    k_fc<<<dim3(64), dim3(32), 0, stream>>>(hsm, fc_w, fc_b, out);
}